// Round 1
// baseline (388.619 us; speedup 1.0000x reference)
//
#include <hip/hip_runtime.h>

// Bahdanau additive attention: B=8, TE=512, TD=256, H=256, fp32.
//   We = enc @ W_a  [B,TE,H];  Uh = dec @ U_a  [B,TD,H]
//   e[b,j,i] = softmax_i( sum_h V[h]*tanh(We[b,i,h]+Uh[b,j,h]) )
//   c[b,j,h] = sum_i e[b,j,i]*enc[b,i,h]
// Outputs concatenated: d_out[0 : B*TD*H] = c, then [B*TD*TE] = e.

#define BB 8
#define TE 512
#define TD 256
#define HH 256

#if __has_builtin(__builtin_amdgcn_exp2f)
#define EXP2F(x) __builtin_amdgcn_exp2f(x)
#else
#define EXP2F(x) exp2f(x)
#endif
#define RCPF(x) __builtin_amdgcn_rcpf(x)

// ---------------------------------------------------------------------------
// Kernel 1: row GEMMs for We and Uh, output pre-scaled by K = 2*log2(e) so
// the main kernel's tanh is exp2-only:  tanh(x) = 1 - 2/(exp2(K*x)+1).
// 8 rows per block; thread t owns output column t; W reads coalesced.
// ---------------------------------------------------------------------------
__global__ __launch_bounds__(256) void k_pregemm(
    const float* __restrict__ enc, const float* __restrict__ dec,
    const float* __restrict__ Wa,  const float* __restrict__ Ua,
    float* __restrict__ We, float* __restrict__ Uh)
{
    const float KS = 2.8853900817779268f;  // 2*log2(e)
    int r0 = blockIdx.x * 8;
    const float* in; const float* W; float* out;
    if (r0 < BB * TE) {
        in = enc + (size_t)r0 * HH;  W = Wa;  out = We + (size_t)r0 * HH;
    } else {
        int r = r0 - BB * TE;
        in = dec + (size_t)r * HH;   W = Ua;  out = Uh + (size_t)r * HH;
    }
    __shared__ float s_in[8][HH];
    int tid = threadIdx.x;
    #pragma unroll
    for (int r = 0; r < 8; r++) s_in[r][tid] = in[r * HH + tid];
    __syncthreads();

    float acc[8] = {0.f,0.f,0.f,0.f,0.f,0.f,0.f,0.f};
    #pragma unroll 4
    for (int k = 0; k < HH; k++) {
        float w = W[k * HH + tid];
        #pragma unroll
        for (int r = 0; r < 8; r++) acc[r] = fmaf(s_in[r][k], w, acc[r]);
    }
    #pragma unroll
    for (int r = 0; r < 8; r++) out[r * HH + tid] = acc[r] * KS;
}

// ---------------------------------------------------------------------------
// Kernel 2: one wave per decoder position j (4 j's per 256-thread block).
// Lane l owns columns h = 4l..4l+3 (float4).  Phase A: energies via
// coalesced We-row loads + butterfly reduce.  Softmax wave-local.  Phase B:
// c accumulation with float4 enc loads.  No __syncthreads needed anywhere.
// ---------------------------------------------------------------------------
__global__ __launch_bounds__(256) void k_attn(
    const float* __restrict__ enc, const float* __restrict__ We,
    const float* __restrict__ Uh,  const float* __restrict__ Va,
    float* __restrict__ out_c, float* __restrict__ out_e)
{
    const float L2E = 1.4426950408889634f;  // log2(e)
    int blk  = blockIdx.x;        // 512 blocks
    int b    = blk >> 6;          // TD/4 = 64 blocks per batch
    int j    = ((blk & 63) << 2) + (threadIdx.x >> 6);
    int lane = threadIdx.x & 63;
    int bj   = b * TD + j;
    int wv   = threadIdx.x >> 6;

    __shared__ float s_e[4][TE];  // per-wave probability rows

    // V scaled by log2(e): energies come out pre-scaled for exp2-softmax.
    float4 v4 = *(const float4*)(Va + 4 * lane);
    float vL0 = v4.x * L2E, vL1 = v4.y * L2E, vL2 = v4.z * L2E, vL3 = v4.w * L2E;
    float n0 = -2.f * vL0, n1 = -2.f * vL1, n2 = -2.f * vL2, n3 = -2.f * vL3;
    // Uh row (already scaled by 2*log2(e) in k_pregemm)
    float4 u4 = *(const float4*)(Uh + (size_t)bj * HH + 4 * lane);

    const float* Wb = We + (size_t)b * TE * HH + 4 * lane;

    // ---- Phase A: energies for all i -------------------------------------
    #pragma unroll 2
    for (int i = 0; i < TE; i++) {
        float4 w4 = *(const float4*)(Wb + (size_t)i * HH);
        float t, r, p;
        t = EXP2F(w4.x + u4.x); r = RCPF(t + 1.f); p  = fmaf(n0, r, vL0);
        t = EXP2F(w4.y + u4.y); r = RCPF(t + 1.f); p += fmaf(n1, r, vL1);
        t = EXP2F(w4.z + u4.z); r = RCPF(t + 1.f); p += fmaf(n2, r, vL2);
        t = EXP2F(w4.w + u4.w); r = RCPF(t + 1.f); p += fmaf(n3, r, vL3);
        #pragma unroll
        for (int off = 32; off; off >>= 1) p += __shfl_xor(p, off, 64);
        if (lane == 0) s_e[wv][i] = p;   // wave-local; LDS in-order per wave
    }

    // ---- Softmax over i (wave-local) -------------------------------------
    float ev[8];
    float m = -3.0e38f;
    #pragma unroll
    for (int k = 0; k < 8; k++) {
        ev[k] = s_e[wv][lane + 64 * k];
        m = fmaxf(m, ev[k]);
    }
    #pragma unroll
    for (int off = 32; off; off >>= 1) m = fmaxf(m, __shfl_xor(m, off, 64));
    float s = 0.f;
    #pragma unroll
    for (int k = 0; k < 8; k++) { ev[k] = EXP2F(ev[k] - m); s += ev[k]; }
    #pragma unroll
    for (int off = 32; off; off >>= 1) s += __shfl_xor(s, off, 64);
    float rs = RCPF(s);

    float* oe = out_e + (size_t)bj * TE;
    #pragma unroll
    for (int k = 0; k < 8; k++) {
        float pr = ev[k] * rs;
        s_e[wv][lane + 64 * k] = pr;
        oe[lane + 64 * k] = pr;
    }

    // ---- Phase B: c[b,j,:] = sum_i e_i * enc[b,i,:] ----------------------
    const float* eb = enc + (size_t)b * TE * HH + 4 * lane;
    float ax = 0.f, ay = 0.f, az = 0.f, aw = 0.f;
    #pragma unroll 4
    for (int i = 0; i < TE; i++) {
        float pe = s_e[wv][i];           // LDS broadcast (own wave's row)
        float4 e4 = *(const float4*)(eb + (size_t)i * HH);
        ax = fmaf(pe, e4.x, ax);
        ay = fmaf(pe, e4.y, ay);
        az = fmaf(pe, e4.z, az);
        aw = fmaf(pe, e4.w, aw);
    }
    float4 o; o.x = ax; o.y = ay; o.z = az; o.w = aw;
    *(float4*)(out_c + (size_t)bj * HH + 4 * lane) = o;
}

extern "C" void kernel_launch(void* const* d_in, const int* in_sizes, int n_in,
                              void* d_out, int out_size, void* d_ws, size_t ws_size,
                              hipStream_t stream) {
    const float* enc = (const float*)d_in[0];  // [B,TE,H]
    const float* dec = (const float*)d_in[1];  // [B,TD,H]
    const float* Wa  = (const float*)d_in[2];  // [H,H]
    const float* Ua  = (const float*)d_in[3];  // [H,H]
    const float* Va  = (const float*)d_in[4];  // [H,1]

    float* We = (float*)d_ws;                          // B*TE*H floats
    float* Uh = We + (size_t)BB * TE * HH;             // B*TD*H floats

    float* out_c = (float*)d_out;                      // [B,TD,H]
    float* out_e = out_c + (size_t)BB * TD * HH;       // [B,TD,TE]

    int rows = BB * TE + BB * TD;                      // 6144
    k_pregemm<<<rows / 8, 256, 0, stream>>>(enc, dec, Wa, Ua, We, Uh);
    k_attn<<<BB * TD / 4, 256, 0, stream>>>(enc, We, Uh, Va, out_c, out_e);
}

// Round 2
// 178.500 us; speedup vs baseline: 2.1771x; 2.1771x over previous
//
#include <hip/hip_runtime.h>

// Bahdanau additive attention: B=8, TE=512, TD=256, H=256, fp32.
//   We = enc @ W_a; Uh = dec @ U_a
//   e[b,j,i] = softmax_i( sum_h V[h]*tanh(We[b,i,h]+Uh[b,j,h]) )
//   c[b,j,h] = sum_i e[b,j,i]*enc[b,i,h]
// d_out = [c (B*TD*H)] ++ [e (B*TD*TE)]
//
// R1 structure: k_pre writes WeT[b][h][i] (TRANSPOSED, scaled by 2*log2(e))
// so k_attn can put encoder position i in the lane dimension: energies
// accumulate per-lane (no per-i butterfly), WeT loads coalesced, Uh/V are
// wave-uniform scalar loads. tanh via exp2-only: tanh(x)=1-2/(exp2(Kx)+1),
// constant term dropped (softmax shift-invariant).

#define BB 8
#define TE 512
#define TD 256
#define HH 256

#define EXP2F(x) __builtin_amdgcn_exp2f(x)
#define RCPF(x)  __builtin_amdgcn_rcpf(x)
#define KSCALE   2.8853900817779268f   // 2*log2(e)
#define L2E      1.4426950408889634f   // log2(e)

// ---------------------------------------------------------------------------
// k_pre: blocks [0,128): enc rows -> WeT[b][h][i] (scaled), LDS transpose.
//        blocks [128,192): dec rows -> Uh[bj][h] (scaled), direct store.
// Block = 4 waves x 8 rows = 32 rows. Lane owns 4 output cols (float4 W).
// X reads are wave-uniform (scalar-load path); no LDS in the k-loop.
// ---------------------------------------------------------------------------
__global__ __launch_bounds__(256) void k_pre(
    const float* __restrict__ enc, const float* __restrict__ dec,
    const float* __restrict__ Wa,  const float* __restrict__ Ua,
    float* __restrict__ WeT, float* __restrict__ Uh)
{
    const int wv = threadIdx.x >> 6, lane = threadIdx.x & 63;
    const bool is_enc = (blockIdx.x < 128);
    int row0;
    const float* X;
    const float* W;
    if (is_enc) { row0 = blockIdx.x * 32 + wv * 8;         X = enc; W = Wa; }
    else        { row0 = (blockIdx.x - 128) * 32 + wv * 8; X = dec; W = Ua; }

    const float* xb = X + (size_t)row0 * HH;
    const float* Wl = W + 4 * lane;

    float4 acc[8];
    #pragma unroll
    for (int r = 0; r < 8; r++) { acc[r].x = acc[r].y = acc[r].z = acc[r].w = 0.f; }

    #pragma unroll 4
    for (int k = 0; k < HH; k++) {
        float4 w4 = *(const float4*)(Wl + (size_t)k * HH);
        #pragma unroll
        for (int r = 0; r < 8; r++) {
            float x = xb[r * HH + k];          // wave-uniform -> s_load
            acc[r].x = fmaf(x, w4.x, acc[r].x);
            acc[r].y = fmaf(x, w4.y, acc[r].y);
            acc[r].z = fmaf(x, w4.z, acc[r].z);
            acc[r].w = fmaf(x, w4.w, acc[r].w);
        }
    }
    #pragma unroll
    for (int r = 0; r < 8; r++) {
        acc[r].x *= KSCALE; acc[r].y *= KSCALE;
        acc[r].z *= KSCALE; acc[r].w *= KSCALE;
    }

    __shared__ float s_t[32][260];   // 260: 16B-aligned row stride, bank-skew 4

    if (is_enc) {
        #pragma unroll
        for (int r = 0; r < 8; r++)
            *(float4*)&s_t[wv * 8 + r][4 * lane] = acc[r];
        __syncthreads();
        const int t  = threadIdx.x;             // h column
        const int b  = blockIdx.x >> 4;         // 16 blocks per batch
        const int i0 = (blockIdx.x * 32) & 511; // i-tile base within batch
        float* dst = WeT + ((size_t)b * HH + t) * TE + i0;
        #pragma unroll
        for (int g = 0; g < 8; g++) {
            float4 v;
            v.x = s_t[4 * g + 0][t];
            v.y = s_t[4 * g + 1][t];
            v.z = s_t[4 * g + 2][t];
            v.w = s_t[4 * g + 3][t];
            *(float4*)(dst + 4 * g) = v;
        }
    } else {
        float* dst = Uh + (size_t)row0 * HH + 4 * lane;
        #pragma unroll
        for (int r = 0; r < 8; r++)
            *(float4*)(dst + (size_t)r * HH) = acc[r];
    }
}

// ---------------------------------------------------------------------------
// k_attn: one wave per decoder position j (4 per block). Lane l owns
// i in {4l..4l+3, 256+4l..256+4l+3}. Phase A: loop h, coalesced WeT row
// loads, per-lane energy accumulation (8 independent chains, no reduce).
// Softmax: lane-local + one butterfly. Phase B: c accumulation, float4.
// ---------------------------------------------------------------------------
__global__ __launch_bounds__(256) void k_attn(
    const float* __restrict__ enc, const float* __restrict__ WeT,
    const float* __restrict__ Uh,  const float* __restrict__ Va,
    float* __restrict__ out_c, float* __restrict__ out_e)
{
    const int wv = threadIdx.x >> 6, lane = threadIdx.x & 63;
    const int jj = blockIdx.x * 4 + wv;   // 0..2047 (= b*TD + j)
    const int b  = jj >> 8;

    __shared__ float s_e[4][TE];          // per-wave probability rows (8 KB)

    const float* WT = WeT + (size_t)b * HH * TE + 4 * lane;
    const float* ur = Uh + (size_t)jj * HH;
    const float  nsc = -2.0f * L2E;

    float a0 = 0.f, a1 = 0.f, a2 = 0.f, a3 = 0.f;
    float a4 = 0.f, a5 = 0.f, a6 = 0.f, a7 = 0.f;

    #pragma unroll 4
    for (int h = 0; h < HH; h++) {
        float u  = ur[h];                 // wave-uniform -> s_load
        float nh = Va[h] * nsc;           // wave-uniform
        const float* wp = WT + (size_t)h * TE;
        float4 wa = *(const float4*)(wp);
        float4 wb = *(const float4*)(wp + 256);
        a0 = fmaf(nh, RCPF(EXP2F(wa.x + u) + 1.f), a0);
        a1 = fmaf(nh, RCPF(EXP2F(wa.y + u) + 1.f), a1);
        a2 = fmaf(nh, RCPF(EXP2F(wa.z + u) + 1.f), a2);
        a3 = fmaf(nh, RCPF(EXP2F(wa.w + u) + 1.f), a3);
        a4 = fmaf(nh, RCPF(EXP2F(wb.x + u) + 1.f), a4);
        a5 = fmaf(nh, RCPF(EXP2F(wb.y + u) + 1.f), a5);
        a6 = fmaf(nh, RCPF(EXP2F(wb.z + u) + 1.f), a6);
        a7 = fmaf(nh, RCPF(EXP2F(wb.w + u) + 1.f), a7);
    }

    // ---- softmax over i (lane-local 8 + one butterfly) -------------------
    float m = fmaxf(fmaxf(fmaxf(a0, a1), fmaxf(a2, a3)),
                    fmaxf(fmaxf(a4, a5), fmaxf(a6, a7)));
    #pragma unroll
    for (int off = 32; off; off >>= 1) m = fmaxf(m, __shfl_xor(m, off, 64));
    float e0 = EXP2F(a0 - m), e1 = EXP2F(a1 - m), e2 = EXP2F(a2 - m), e3 = EXP2F(a3 - m);
    float e4 = EXP2F(a4 - m), e5 = EXP2F(a5 - m), e6 = EXP2F(a6 - m), e7 = EXP2F(a7 - m);
    float s = ((e0 + e1) + (e2 + e3)) + ((e4 + e5) + (e6 + e7));
    #pragma unroll
    for (int off = 32; off; off >>= 1) s += __shfl_xor(s, off, 64);
    float rs = RCPF(s);

    float4 p0, p1;
    p0.x = e0 * rs; p0.y = e1 * rs; p0.z = e2 * rs; p0.w = e3 * rs;
    p1.x = e4 * rs; p1.y = e5 * rs; p1.z = e6 * rs; p1.w = e7 * rs;

    float* oe = out_e + (size_t)jj * TE;
    *(float4*)(oe + 4 * lane)       = p0;
    *(float4*)(oe + 256 + 4 * lane) = p1;
    *(float4*)&s_e[wv][4 * lane]       = p0;   // wave-local, no barrier needed
    *(float4*)&s_e[wv][256 + 4 * lane] = p1;

    // ---- Phase B: c[b,j,:] = sum_i e_i * enc[b,i,:] ----------------------
    const float* eb = enc + (size_t)b * TE * HH + 4 * lane;
    float cx = 0.f, cy = 0.f, cz = 0.f, cw = 0.f;
    #pragma unroll 2
    for (int i4 = 0; i4 < TE / 4; i4++) {
        float4 pe = *(const float4*)&s_e[wv][4 * i4];
        const float* ep = eb + (size_t)i4 * 4 * HH;
        float4 q0 = *(const float4*)(ep);
        float4 q1 = *(const float4*)(ep + HH);
        float4 q2 = *(const float4*)(ep + 2 * HH);
        float4 q3 = *(const float4*)(ep + 3 * HH);
        cx = fmaf(pe.x, q0.x, cx); cy = fmaf(pe.x, q0.y, cy);
        cz = fmaf(pe.x, q0.z, cz); cw = fmaf(pe.x, q0.w, cw);
        cx = fmaf(pe.y, q1.x, cx); cy = fmaf(pe.y, q1.y, cy);
        cz = fmaf(pe.y, q1.z, cz); cw = fmaf(pe.y, q1.w, cw);
        cx = fmaf(pe.z, q2.x, cx); cy = fmaf(pe.z, q2.y, cy);
        cz = fmaf(pe.z, q2.z, cz); cw = fmaf(pe.z, q2.w, cw);
        cx = fmaf(pe.w, q3.x, cx); cy = fmaf(pe.w, q3.y, cy);
        cz = fmaf(pe.w, q3.z, cz); cw = fmaf(pe.w, q3.w, cw);
    }
    float4 o; o.x = cx; o.y = cy; o.z = cz; o.w = cw;
    *(float4*)(out_c + (size_t)jj * HH + 4 * lane) = o;
}

extern "C" void kernel_launch(void* const* d_in, const int* in_sizes, int n_in,
                              void* d_out, int out_size, void* d_ws, size_t ws_size,
                              hipStream_t stream) {
    const float* enc = (const float*)d_in[0];
    const float* dec = (const float*)d_in[1];
    const float* Wa  = (const float*)d_in[2];
    const float* Ua  = (const float*)d_in[3];
    const float* Va  = (const float*)d_in[4];

    float* WeT = (float*)d_ws;                       // B*H*TE floats (4 MB)
    float* Uh  = WeT + (size_t)BB * HH * TE;         // B*TD*H floats (2 MB)

    float* out_c = (float*)d_out;                    // [B,TD,H]
    float* out_e = out_c + (size_t)BB * TD * HH;     // [B,TD,TE]

    k_pre<<<192, 256, 0, stream>>>(enc, dec, Wa, Ua, WeT, Uh);
    k_attn<<<BB * TD / 4, 256, 0, stream>>>(enc, WeT, Uh, Va, out_c, out_e);
}

// Round 3
// 163.493 us; speedup vs baseline: 2.3770x; 1.0918x over previous
//
#include <hip/hip_runtime.h>

// Bahdanau additive attention: B=8, TE=512, TD=256, H=256, fp32.
//   We = enc @ W_a; Uh = dec @ U_a
//   e[b,j,i] = softmax_i( sum_h V[h]*tanh(We[b,i,h]+Uh[b,j,h]) )
//   c[b,j,h] = sum_i e[b,j,i]*enc[b,i,h]
// d_out = [c (B*TD*H)] ++ [e (B*TD*TE)]
//
// R2: k_pre = LDS-tiled fp32 GEMM (64x64 tile, Kc=32, 4x4 per thread),
// writes WeT[b][h][i] transposed+scaled and Uh scaled. k_attn: block owns
// 4 j's; each wave covers 128 i's for all 4 j's -> WeT/enc read once per
// block (4x less L2 traffic), Uh/Va block-uniform -> s_load.

#define BB 8
#define TE 512
#define TD 256
#define HH 256

#define EXP2F(x) __builtin_amdgcn_exp2f(x)
#define RCPF(x)  __builtin_amdgcn_rcpf(x)
#define KSCALE   2.8853900817779268f   // 2*log2(e)
#define L2E      1.4426950408889634f   // log2(e)

// ---------------------------------------------------------------------------
// k_pre: C[6144x256] = [enc;dec] @ [Wa|Ua], scaled by KSCALE.
// Blocks 0..255: enc -> WeT[b][h][i] (transposed store).
// Blocks 256..383: dec -> Uh[row][h] (direct store).
// ---------------------------------------------------------------------------
__global__ __launch_bounds__(256) void k_pre(
    const float* __restrict__ enc, const float* __restrict__ dec,
    const float* __restrict__ Wa,  const float* __restrict__ Ua,
    float* __restrict__ WeT, float* __restrict__ Uh)
{
    const int tid = threadIdx.x;
    const bool is_enc = blockIdx.x < 256;
    const int bi = is_enc ? blockIdx.x : (blockIdx.x - 256);
    const int m0 = (bi >> 2) * 64;     // row-tile base
    const int n0 = (bi & 3) * 64;      // col-tile base
    const float* X = is_enc ? enc : dec;
    const float* W = is_enc ? Wa : Ua;

    __shared__ float Xs[32][68];       // [k][row], 68: 16B-aligned + skew
    __shared__ float Ws[32][68];       // [k][col]

    const int kq = tid & 7,  xr = tid >> 3;        // X staging
    const int wk = tid >> 3, wn = (tid & 7) * 8;   // W staging
    const int tx = tid & 15, ty = tid >> 4;        // compute: 4 cols, 4 rows

    float acc[4][4];
    #pragma unroll
    for (int r = 0; r < 4; r++)
        #pragma unroll
        for (int c = 0; c < 4; c++) acc[r][c] = 0.f;

    for (int kc = 0; kc < HH; kc += 32) {
        float4 xa = *(const float4*)(X + (size_t)(m0 + xr) * HH + kc + kq * 4);
        float4 xb = *(const float4*)(X + (size_t)(m0 + xr + 32) * HH + kc + kq * 4);
        float4 wa = *(const float4*)(W + (size_t)(kc + wk) * HH + n0 + wn);
        float4 wb = *(const float4*)(W + (size_t)(kc + wk) * HH + n0 + wn + 4);
        __syncthreads();               // prev chunk fully consumed
        Xs[kq * 4 + 0][xr] = xa.x; Xs[kq * 4 + 1][xr] = xa.y;
        Xs[kq * 4 + 2][xr] = xa.z; Xs[kq * 4 + 3][xr] = xa.w;
        Xs[kq * 4 + 0][xr + 32] = xb.x; Xs[kq * 4 + 1][xr + 32] = xb.y;
        Xs[kq * 4 + 2][xr + 32] = xb.z; Xs[kq * 4 + 3][xr + 32] = xb.w;
        *(float4*)&Ws[wk][wn]     = wa;
        *(float4*)&Ws[wk][wn + 4] = wb;
        __syncthreads();
        #pragma unroll
        for (int k = 0; k < 32; k++) {
            float4 a = *(const float4*)&Xs[k][ty * 4];
            float4 b = *(const float4*)&Ws[k][tx * 4];
            acc[0][0] = fmaf(a.x, b.x, acc[0][0]); acc[0][1] = fmaf(a.x, b.y, acc[0][1]);
            acc[0][2] = fmaf(a.x, b.z, acc[0][2]); acc[0][3] = fmaf(a.x, b.w, acc[0][3]);
            acc[1][0] = fmaf(a.y, b.x, acc[1][0]); acc[1][1] = fmaf(a.y, b.y, acc[1][1]);
            acc[1][2] = fmaf(a.y, b.z, acc[1][2]); acc[1][3] = fmaf(a.y, b.w, acc[1][3]);
            acc[2][0] = fmaf(a.z, b.x, acc[2][0]); acc[2][1] = fmaf(a.z, b.y, acc[2][1]);
            acc[2][2] = fmaf(a.z, b.z, acc[2][2]); acc[2][3] = fmaf(a.z, b.w, acc[2][3]);
            acc[3][0] = fmaf(a.w, b.x, acc[3][0]); acc[3][1] = fmaf(a.w, b.y, acc[3][1]);
            acc[3][2] = fmaf(a.w, b.z, acc[3][2]); acc[3][3] = fmaf(a.w, b.w, acc[3][3]);
        }
    }

    if (is_enc) {
        const int b  = m0 >> 9;                 // 512 enc rows per batch
        const int ib = (m0 & 511) + ty * 4;     // i base for this thread
        #pragma unroll
        for (int c = 0; c < 4; c++) {
            float4 v;
            v.x = acc[0][c] * KSCALE; v.y = acc[1][c] * KSCALE;
            v.z = acc[2][c] * KSCALE; v.w = acc[3][c] * KSCALE;
            *(float4*)(WeT + ((size_t)b * HH + n0 + tx * 4 + c) * TE + ib) = v;
        }
    } else {
        #pragma unroll
        for (int r = 0; r < 4; r++) {
            float4 v;
            v.x = acc[r][0] * KSCALE; v.y = acc[r][1] * KSCALE;
            v.z = acc[r][2] * KSCALE; v.w = acc[r][3] * KSCALE;
            *(float4*)(Uh + (size_t)(m0 + ty * 4 + r) * HH + n0 + tx * 4) = v;
        }
    }
}

// ---------------------------------------------------------------------------
// k_attn: block owns 4 consecutive j's (same b); wave w covers
// i in [128w,128w+128), 2 i/lane, accumulating energies for ALL 4 j's
// (8 independent chains/lane). Cross-wave softmax via LDS, one barrier.
// Phase B: wave w computes c for j0+w over all 512 i.
// ---------------------------------------------------------------------------
__global__ __launch_bounds__(256) void k_attn(
    const float* __restrict__ enc, const float* __restrict__ WeT,
    const float* __restrict__ Uh,  const float* __restrict__ Va,
    float* __restrict__ out_c, float* __restrict__ out_e)
{
    const int wv = threadIdx.x >> 6, lane = threadIdx.x & 63;
    const int b   = blockIdx.x >> 6;          // 64 blocks per batch
    const int j0  = (blockIdx.x & 63) * 4;    // first of 4 j's
    const int jj0 = b * TD + j0;              // block-uniform

    __shared__ float sE[4][TE];               // energies -> probs, per j

    const float nsc = -2.0f * L2E;
    const int i0 = 128 * wv + 2 * lane;

    const float* wt = WeT + (size_t)b * HH * TE + i0;
    const float* u0 = Uh + (size_t)jj0 * HH;  // block-uniform -> s_load path

    float a00 = 0.f, a01 = 0.f, a10 = 0.f, a11 = 0.f;
    float a20 = 0.f, a21 = 0.f, a30 = 0.f, a31 = 0.f;

    #pragma unroll 4
    for (int h = 0; h < HH; h++) {
        float nh = Va[h] * nsc;                       // uniform
        float u_0 = u0[h];                            // uniform
        float u_1 = u0[HH + h];
        float u_2 = u0[2 * HH + h];
        float u_3 = u0[3 * HH + h];
        float2 w2 = *(const float2*)(wt + (size_t)h * TE);
        a00 = fmaf(nh, RCPF(EXP2F(w2.x + u_0) + 1.f), a00);
        a01 = fmaf(nh, RCPF(EXP2F(w2.y + u_0) + 1.f), a01);
        a10 = fmaf(nh, RCPF(EXP2F(w2.x + u_1) + 1.f), a10);
        a11 = fmaf(nh, RCPF(EXP2F(w2.y + u_1) + 1.f), a11);
        a20 = fmaf(nh, RCPF(EXP2F(w2.x + u_2) + 1.f), a20);
        a21 = fmaf(nh, RCPF(EXP2F(w2.y + u_2) + 1.f), a21);
        a30 = fmaf(nh, RCPF(EXP2F(w2.x + u_3) + 1.f), a30);
        a31 = fmaf(nh, RCPF(EXP2F(w2.y + u_3) + 1.f), a31);
    }

    float2 e0; e0.x = a00; e0.y = a01; *(float2*)&sE[0][i0] = e0;
    float2 e1; e1.x = a10; e1.y = a11; *(float2*)&sE[1][i0] = e1;
    float2 e2; e2.x = a20; e2.y = a21; *(float2*)&sE[2][i0] = e2;
    float2 e3; e3.x = a30; e3.y = a31; *(float2*)&sE[3][i0] = e3;
    __syncthreads();

    // ---- softmax: wave w handles j0+w --------------------------------
    float ev[8];
    float m = -3.0e38f;
    #pragma unroll
    for (int k = 0; k < 8; k++) {
        ev[k] = sE[wv][lane + 64 * k];
        m = fmaxf(m, ev[k]);
    }
    #pragma unroll
    for (int off = 32; off; off >>= 1) m = fmaxf(m, __shfl_xor(m, off, 64));
    float s = 0.f;
    #pragma unroll
    for (int k = 0; k < 8; k++) { ev[k] = EXP2F(ev[k] - m); s += ev[k]; }
    #pragma unroll
    for (int off = 32; off; off >>= 1) s += __shfl_xor(s, off, 64);
    float rs = RCPF(s);

    float* oe = out_e + (size_t)(jj0 + wv) * TE;
    #pragma unroll
    for (int k = 0; k < 8; k++) {
        float p = ev[k] * rs;
        sE[wv][lane + 64 * k] = p;    // own wave's row; read back below
        oe[lane + 64 * k] = p;
    }

    // ---- Phase B: c[jj0+wv][:] = sum_i p_i * enc[b,i,:] --------------
    const float* eb = enc + (size_t)b * TE * HH + 4 * lane;
    float cx = 0.f, cy = 0.f, cz = 0.f, cw = 0.f;
    #pragma unroll 2
    for (int i4 = 0; i4 < TE / 4; i4++) {
        float4 pe = *(const float4*)&sE[wv][4 * i4];    // uniform broadcast
        const float* ep = eb + (size_t)i4 * 4 * HH;
        float4 q0 = *(const float4*)(ep);
        float4 q1 = *(const float4*)(ep + HH);
        float4 q2 = *(const float4*)(ep + 2 * HH);
        float4 q3 = *(const float4*)(ep + 3 * HH);
        cx = fmaf(pe.x, q0.x, cx); cy = fmaf(pe.x, q0.y, cy);
        cz = fmaf(pe.x, q0.z, cz); cw = fmaf(pe.x, q0.w, cw);
        cx = fmaf(pe.y, q1.x, cx); cy = fmaf(pe.y, q1.y, cy);
        cz = fmaf(pe.y, q1.z, cz); cw = fmaf(pe.y, q1.w, cw);
        cx = fmaf(pe.z, q2.x, cx); cy = fmaf(pe.z, q2.y, cy);
        cz = fmaf(pe.z, q2.z, cz); cw = fmaf(pe.z, q2.w, cw);
        cx = fmaf(pe.w, q3.x, cx); cy = fmaf(pe.w, q3.y, cy);
        cz = fmaf(pe.w, q3.z, cz); cw = fmaf(pe.w, q3.w, cw);
    }
    float4 o; o.x = cx; o.y = cy; o.z = cz; o.w = cw;
    *(float4*)(out_c + (size_t)(jj0 + wv) * HH + 4 * lane) = o;
}

extern "C" void kernel_launch(void* const* d_in, const int* in_sizes, int n_in,
                              void* d_out, int out_size, void* d_ws, size_t ws_size,
                              hipStream_t stream) {
    const float* enc = (const float*)d_in[0];
    const float* dec = (const float*)d_in[1];
    const float* Wa  = (const float*)d_in[2];
    const float* Ua  = (const float*)d_in[3];
    const float* Va  = (const float*)d_in[4];

    float* WeT = (float*)d_ws;                       // B*H*TE floats (4 MB)
    float* Uh  = WeT + (size_t)BB * HH * TE;         // B*TD*H floats (2 MB)

    float* out_c = (float*)d_out;                    // [B,TD,H]
    float* out_e = out_c + (size_t)BB * TD * HH;     // [B,TD,TE]

    k_pre<<<384, 256, 0, stream>>>(enc, dec, Wa, Ua, WeT, Uh);
    k_attn<<<BB * TD / 4, 256, 0, stream>>>(enc, WeT, Uh, Va, out_c, out_e);
}

// Round 4
// 126.518 us; speedup vs baseline: 3.0716x; 1.2922x over previous
//
#include <hip/hip_runtime.h>

// Bahdanau additive attention: B=8, TE=512, TD=256, H=256, fp32.
//   We = enc @ W_a; Uh = dec @ U_a
//   e[b,j,i] = softmax_i( sum_h V[h]*tanh(We[b,i,h]+Uh[b,j,h]) )
//   c[b,j,h] = sum_i e[b,j,i]*enc[b,i,h]
// d_out = [c (B*TD*H)] ++ [e (B*TD*TE)]
//
// R3 key identity: tanh(x) = 1 - 2/(1+exp2(K x)), K=2*log2(e), and
// exp2(K(w+u)) = exp2(Kw)*exp2(Ku). k_pre stores W~ = exp2(K*We)^T and
// U~ = exp2(K*Uh); k_attn's inner element is then fma(w,u,1)+rcp+fma:
// ONE transcendental per element (was two) -> trans-pipe floor ~14 us.
// k_attn: 512-thread blocks (8 waves, 4 j, 1 i/lane) -> 4 waves/SIMD.

#define BB 8
#define TE 512
#define TD 256
#define HH 256

#define EXP2F(x) __builtin_amdgcn_exp2f(x)
#define RCPF(x)  __builtin_amdgcn_rcpf(x)
#define KSCALE   2.8853900817779268f   // 2*log2(e)
#define NSC      (-2.8853900817779268f) // -2*log2(e): energy = NSC*sum(v*r)

// ---------------------------------------------------------------------------
// k_pre: C = [enc;dec] @ [Wa|Ua]; store exp2(KSCALE*C).
// Blocks 0..255: enc -> WeT[b][h][i] (transposed). 256..383: dec -> Uh.
// 64x64 tile, Kc=32, 4x4 per thread.
// ---------------------------------------------------------------------------
__global__ __launch_bounds__(256) void k_pre(
    const float* __restrict__ enc, const float* __restrict__ dec,
    const float* __restrict__ Wa,  const float* __restrict__ Ua,
    float* __restrict__ WeT, float* __restrict__ Uh)
{
    const int tid = threadIdx.x;
    const bool is_enc = blockIdx.x < 256;
    const int bi = is_enc ? blockIdx.x : (blockIdx.x - 256);
    const int m0 = (bi >> 2) * 64;
    const int n0 = (bi & 3) * 64;
    const float* X = is_enc ? enc : dec;
    const float* W = is_enc ? Wa : Ua;

    __shared__ float Xs[32][68];
    __shared__ float Ws[32][68];

    const int kq = tid & 7,  xr = tid >> 3;
    const int wk = tid >> 3, wn = (tid & 7) * 8;
    const int tx = tid & 15, ty = tid >> 4;

    float acc[4][4];
    #pragma unroll
    for (int r = 0; r < 4; r++)
        #pragma unroll
        for (int c = 0; c < 4; c++) acc[r][c] = 0.f;

    for (int kc = 0; kc < HH; kc += 32) {
        float4 xa = *(const float4*)(X + (size_t)(m0 + xr) * HH + kc + kq * 4);
        float4 xb = *(const float4*)(X + (size_t)(m0 + xr + 32) * HH + kc + kq * 4);
        float4 wa = *(const float4*)(W + (size_t)(kc + wk) * HH + n0 + wn);
        float4 wb = *(const float4*)(W + (size_t)(kc + wk) * HH + n0 + wn + 4);
        __syncthreads();
        Xs[kq * 4 + 0][xr] = xa.x; Xs[kq * 4 + 1][xr] = xa.y;
        Xs[kq * 4 + 2][xr] = xa.z; Xs[kq * 4 + 3][xr] = xa.w;
        Xs[kq * 4 + 0][xr + 32] = xb.x; Xs[kq * 4 + 1][xr + 32] = xb.y;
        Xs[kq * 4 + 2][xr + 32] = xb.z; Xs[kq * 4 + 3][xr + 32] = xb.w;
        *(float4*)&Ws[wk][wn]     = wa;
        *(float4*)&Ws[wk][wn + 4] = wb;
        __syncthreads();
        #pragma unroll
        for (int k = 0; k < 32; k++) {
            float4 a = *(const float4*)&Xs[k][ty * 4];
            float4 b = *(const float4*)&Ws[k][tx * 4];
            acc[0][0] = fmaf(a.x, b.x, acc[0][0]); acc[0][1] = fmaf(a.x, b.y, acc[0][1]);
            acc[0][2] = fmaf(a.x, b.z, acc[0][2]); acc[0][3] = fmaf(a.x, b.w, acc[0][3]);
            acc[1][0] = fmaf(a.y, b.x, acc[1][0]); acc[1][1] = fmaf(a.y, b.y, acc[1][1]);
            acc[1][2] = fmaf(a.y, b.z, acc[1][2]); acc[1][3] = fmaf(a.y, b.w, acc[1][3]);
            acc[2][0] = fmaf(a.z, b.x, acc[2][0]); acc[2][1] = fmaf(a.z, b.y, acc[2][1]);
            acc[2][2] = fmaf(a.z, b.z, acc[2][2]); acc[2][3] = fmaf(a.z, b.w, acc[2][3]);
            acc[3][0] = fmaf(a.w, b.x, acc[3][0]); acc[3][1] = fmaf(a.w, b.y, acc[3][1]);
            acc[3][2] = fmaf(a.w, b.z, acc[3][2]); acc[3][3] = fmaf(a.w, b.w, acc[3][3]);
        }
    }

    if (is_enc) {
        const int b  = m0 >> 9;
        const int ib = (m0 & 511) + ty * 4;
        #pragma unroll
        for (int c = 0; c < 4; c++) {
            float4 v;
            v.x = EXP2F(acc[0][c] * KSCALE); v.y = EXP2F(acc[1][c] * KSCALE);
            v.z = EXP2F(acc[2][c] * KSCALE); v.w = EXP2F(acc[3][c] * KSCALE);
            *(float4*)(WeT + ((size_t)b * HH + n0 + tx * 4 + c) * TE + ib) = v;
        }
    } else {
        #pragma unroll
        for (int r = 0; r < 4; r++) {
            float4 v;
            v.x = EXP2F(acc[r][0] * KSCALE); v.y = EXP2F(acc[r][1] * KSCALE);
            v.z = EXP2F(acc[r][2] * KSCALE); v.w = EXP2F(acc[r][3] * KSCALE);
            *(float4*)(Uh + (size_t)(m0 + ty * 4 + r) * HH + n0 + tx * 4) = v;
        }
    }
}

// ---------------------------------------------------------------------------
// k_attn: 512 threads = 8 waves; block owns 4 consecutive j's (same b).
// Phase A: wave w, lane l -> i = 64w+l; 4 energy accumulators (one per j);
//   inner element: fma(w~,u~,1) -> rcp -> fma(Va[h], r, acc). 1 trans/elem.
// Softmax: waves 0-3, wave w -> j0+w. Phase B: wave w covers i in
//   [64w,64w+64), partial c[4][256] -> LDS reduce across waves.
// ---------------------------------------------------------------------------
__global__ __launch_bounds__(512) void k_attn(
    const float* __restrict__ enc, const float* __restrict__ WeT,
    const float* __restrict__ Uhe, const float* __restrict__ Va,
    float* __restrict__ out_c, float* __restrict__ out_e)
{
    const int wv = threadIdx.x >> 6, lane = threadIdx.x & 63;
    const int b   = blockIdx.x >> 6;          // 64 blocks per batch
    const int j0  = (blockIdx.x & 63) * 4;
    const int jj0 = b * TD + j0;              // block-uniform

    __shared__ float sP[TE][4];     // 8 KB: energies -> probabilities
    __shared__ float sR[8][4][HH];  // 32 KB: phase-B partials

    const int i = (wv << 6) + lane;
    const float* wt = WeT + (size_t)b * HH * TE + i;
    const float* ut = Uhe + (size_t)jj0 * HH;   // block-uniform -> s_load

    float a0 = 0.f, a1 = 0.f, a2 = 0.f, a3 = 0.f;
    #pragma unroll 4
    for (int h = 0; h < HH; h++) {
        float vah = Va[h];                       // uniform
        float u_0 = ut[h];                       // uniform (exp2-domain)
        float u_1 = ut[HH + h];
        float u_2 = ut[2 * HH + h];
        float u_3 = ut[3 * HH + h];
        float w = wt[(size_t)h * TE];            // exp2-domain
        a0 = fmaf(vah, RCPF(fmaf(w, u_0, 1.f)), a0);
        a1 = fmaf(vah, RCPF(fmaf(w, u_1, 1.f)), a1);
        a2 = fmaf(vah, RCPF(fmaf(w, u_2, 1.f)), a2);
        a3 = fmaf(vah, RCPF(fmaf(w, u_3, 1.f)), a3);
    }
    // energies in log2 domain
    float4 E; E.x = NSC * a0; E.y = NSC * a1; E.z = NSC * a2; E.w = NSC * a3;
    *(float4*)&sP[i][0] = E;
    __syncthreads();

    // ---- softmax: wave w in 0..3 handles j = j0+w ------------------------
    if (wv < 4) {
        float ev[8];
        float m = -3.0e38f;
        #pragma unroll
        for (int k = 0; k < 8; k++) {
            ev[k] = sP[lane + 64 * k][wv];
            m = fmaxf(m, ev[k]);
        }
        #pragma unroll
        for (int off = 32; off; off >>= 1) m = fmaxf(m, __shfl_xor(m, off, 64));
        float s = 0.f;
        #pragma unroll
        for (int k = 0; k < 8; k++) { ev[k] = EXP2F(ev[k] - m); s += ev[k]; }
        #pragma unroll
        for (int off = 32; off; off >>= 1) s += __shfl_xor(s, off, 64);
        float rs = RCPF(s);
        float* oe = out_e + (size_t)(jj0 + wv) * TE;
        #pragma unroll
        for (int k = 0; k < 8; k++) {
            float p = ev[k] * rs;
            sP[lane + 64 * k][wv] = p;
            oe[lane + 64 * k] = p;
        }
    }
    __syncthreads();

    // ---- Phase B: wave w accumulates partial c over i in [64w, 64w+64) ---
    const float* eb = enc + ((size_t)b * TE + (wv << 6)) * HH + 4 * lane;
    float4 c0 = {0,0,0,0}, c1 = {0,0,0,0}, c2 = {0,0,0,0}, c3 = {0,0,0,0};
    #pragma unroll 2
    for (int k = 0; k < 64; k++) {
        float4 p = *(const float4*)&sP[(wv << 6) + k][0];  // broadcast
        float4 q = *(const float4*)(eb + (size_t)k * HH);
        c0.x = fmaf(p.x, q.x, c0.x); c0.y = fmaf(p.x, q.y, c0.y);
        c0.z = fmaf(p.x, q.z, c0.z); c0.w = fmaf(p.x, q.w, c0.w);
        c1.x = fmaf(p.y, q.x, c1.x); c1.y = fmaf(p.y, q.y, c1.y);
        c1.z = fmaf(p.y, q.z, c1.z); c1.w = fmaf(p.y, q.w, c1.w);
        c2.x = fmaf(p.z, q.x, c2.x); c2.y = fmaf(p.z, q.y, c2.y);
        c2.z = fmaf(p.z, q.z, c2.z); c2.w = fmaf(p.z, q.w, c2.w);
        c3.x = fmaf(p.w, q.x, c3.x); c3.y = fmaf(p.w, q.y, c3.y);
        c3.z = fmaf(p.w, q.z, c3.z); c3.w = fmaf(p.w, q.w, c3.w);
    }
    *(float4*)&sR[wv][0][4 * lane] = c0;
    *(float4*)&sR[wv][1][4 * lane] = c1;
    *(float4*)&sR[wv][2][4 * lane] = c2;
    *(float4*)&sR[wv][3][4 * lane] = c3;
    __syncthreads();

    // ---- final reduce: wave w -> (j = w&3, h-half = w>>2) ----------------
    {
        const int jr = wv & 3;
        const int h2 = (wv >> 2) * 128 + 2 * lane;
        float sx = 0.f, sy = 0.f;
        #pragma unroll
        for (int ww = 0; ww < 8; ww++) {
            float2 t = *(const float2*)&sR[ww][jr][h2];
            sx += t.x; sy += t.y;
        }
        float2 o; o.x = sx; o.y = sy;
        *(float2*)(out_c + (size_t)(jj0 + jr) * HH + h2) = o;
    }
}

extern "C" void kernel_launch(void* const* d_in, const int* in_sizes, int n_in,
                              void* d_out, int out_size, void* d_ws, size_t ws_size,
                              hipStream_t stream) {
    const float* enc = (const float*)d_in[0];
    const float* dec = (const float*)d_in[1];
    const float* Wa  = (const float*)d_in[2];
    const float* Ua  = (const float*)d_in[3];
    const float* Va  = (const float*)d_in[4];

    float* WeT = (float*)d_ws;                       // exp2-domain, B*H*TE
    float* Uhe = WeT + (size_t)BB * HH * TE;         // exp2-domain, B*TD*H

    float* out_c = (float*)d_out;                    // [B,TD,H]
    float* out_e = out_c + (size_t)BB * TD * HH;     // [B,TD,TE]

    k_pre<<<384, 256, 0, stream>>>(enc, dec, Wa, Ua, WeT, Uhe);
    k_attn<<<BB * TD / 4, 512, 0, stream>>>(enc, WeT, Uhe, Va, out_c, out_e);
}